// Round 16
// baseline (95.320 us; speedup 1.0000x reference)
//
#include <hip/hip_runtime.h>
#include <hip/hip_bf16.h>

#define BB 32
#define CC 128
#define HH 96
#define WW 96
#define BN_EPS 1e-5f

typedef __attribute__((ext_vector_type(8))) short bf16x8_t;
typedef __attribute__((ext_vector_type(4))) float f32x4_t;
typedef __attribute__((ext_vector_type(4), aligned(4))) float f32x4u_t;
typedef __attribute__((ext_vector_type(2))) unsigned int u32x2_t;
typedef __attribute__((ext_vector_type(4))) unsigned int u32x4_t;

// ---------------------------------------------------------------------------
// Prep: W fp32 -> bf16, k-permuted (verified). BN folded to inv/bias.
// ---------------------------------------------------------------------------
__global__ __launch_bounds__(256)
void prep_kernel(const float* __restrict__ pw,
                 const float* __restrict__ g, const float* __restrict__ b,
                 const float* __restrict__ m, const float* __restrict__ v,
                 unsigned short* __restrict__ wper,
                 float* __restrict__ inv, float* __restrict__ bias)
{
    int t = blockIdx.x * 256 + threadIdx.x;
    if (t < CC * CC) {
        int o = t >> 7, cidx = t & 127;
        int kc = cidx >> 5, r = cidx & 31, gg = r >> 3, j = r & 7;
        int c = kc * 32 + gg * 4 + (j & 3) + 16 * (j >> 2);
        __hip_bfloat16 h = __float2bfloat16(pw[o * CC + c]);
        wper[o * CC + cidx] = *reinterpret_cast<unsigned short*>(&h);
    }
    if (t < CC) {
        float iv = g[t] * rsqrtf(v[t] + BN_EPS);
        inv[t] = iv;
        bias[t] = b[t] - m[t] * iv;
    }
}

// ---------------------------------------------------------------------------
// Kernel A (R16): depthwise 3x3, block = (b,cs) FULL PLANE, 6 slab iters,
// software-pipelined like the R13 pw win:
//   iter t: LOADG(slab t+2 -> regs)  [in flight during compute]
//           COMPUTE(buf[t&1], t)     [24 ds_read_b32 + 54 FMA + 3 stores]
//           DSWRITE(buf[(t+1)&1])    [regs loaded at iter t-1; vmcnt waited]
//           barrier                  [one per iter]
// Tile rows padded to 97 floats: stride 96 = 0 mod 32 banks put lanes
// r=0..3 of one col-group in the SAME bank (hard 4-way conflict, R15 bug);
// 97 = 1 mod 32 makes it 2-way = free (m136). Weights SGPR-uniform.
// Grid 4096 = 32b x 128cs, chunked XCD swizzle (4096 % 8 == 0).
// ---------------------------------------------------------------------------
__global__ __launch_bounds__(256, 6)
void dw_kernel(const float* __restrict__ x, const float* __restrict__ kk,
               unsigned short* __restrict__ xn)
{
    __shared__ float tile[2][18 * 97];          // 2 x 6.98 KB
    const int tid = threadIdx.x;

    const unsigned wg  = blockIdx.x;
    const unsigned bid = (wg & 7u) * 512u + (wg >> 3);   // bijective on [0,4096)
    const int cs = bid & 127;
    const int b  = bid >> 7;

    // storage -> actual channel permutation (blockIdx-derived -> SGPR)
    const int kc = cs >> 5, rr = cs & 31, gg = rr >> 3, jj = rr & 7;
    const int c = kc * 32 + gg * 4 + (jj & 3) + 16 * (jj >> 2);

    const float* plane = x + (size_t)(b * CC + c) * (HH * WW);
    unsigned short* xplane = xn + (size_t)(b * CC + cs) * (HH * WW);

    // block-uniform weights -> scalar loads
    const float* kp = kk + (size_t)(b * CC + c) * 9;
    const float kw0 = kp[0], kw1 = kp[1], kw2 = kp[2];
    const float kw3 = kp[3], kw4 = kp[4], kw5 = kp[5];
    const float kw6 = kp[6], kw7 = kp[7], kw8 = kp[8];

    // staging slots: 432 x 16B (18 rows x 24 quads); slot s -> (s/24, (s%24)*4)
    const int sA = tid;          // always < 432
    const int sB = tid + 256;    // valid iff tid < 176
    const int rowA = sA / 24, colA = (sA % 24) * 4;
    const int rowB = sB / 24, colB = (sB % 24) * 4;

    f32x4_t gA[2], gB[2];

    auto LOADG = [&](int t, f32x4_t* gr) {
        const int hhA = t * 16 - 1 + rowA;
        gr[0] = (f32x4_t){0.f, 0.f, 0.f, 0.f};
        if (hhA >= 0 && hhA < HH)
            gr[0] = *(const f32x4_t*)(plane + (size_t)hhA * WW + colA);
        gr[1] = (f32x4_t){0.f, 0.f, 0.f, 0.f};
        if (sB < 432) {
            const int hhB = t * 16 - 1 + rowB;
            if (hhB >= 0 && hhB < HH)
                gr[1] = *(const f32x4_t*)(plane + (size_t)hhB * WW + colB);
        }
    };

    auto DSWRITE = [&](int bufi, f32x4_t* gr) {
        float* d0 = &tile[bufi][rowA * 97 + colA];
        d0[0] = gr[0].x; d0[1] = gr[0].y; d0[2] = gr[0].z; d0[3] = gr[0].w;
        if (sB < 432) {
            float* d1 = &tile[bufi][rowB * 97 + colB];
            d1[0] = gr[1].x; d1[1] = gr[1].y; d1[2] = gr[1].z; d1[3] = gr[1].w;
        }
    };

    const int r  = tid >> 4;            // output row in slab, 0..15
    const int cc = (tid & 15) * 6;      // first col, 0..90

    auto COMPUTE = [&](int bufi, int t) {
        float v[3][8];
        #pragma unroll
        for (int dr = 0; dr < 3; ++dr) {
            const float* trow = &tile[bufi][(r + dr) * 97];
            const float lv = trow[cc == 0 ? 0 : cc - 1];
            v[dr][0] = (cc == 0) ? 0.f : lv;
            #pragma unroll
            for (int i = 0; i < 6; ++i) v[dr][1 + i] = trow[cc + i];
            const float rv = trow[cc == 90 ? 95 : cc + 6];
            v[dr][7] = (cc == 90) ? 0.f : rv;
        }
        unsigned pk[3];
        #pragma unroll
        for (int pr = 0; pr < 3; ++pr) {
            const int j0 = 2 * pr, j1 = j0 + 1;
            float s0 = v[0][j0] * kw0;
            s0 = fmaf(v[0][j0 + 1], kw1, s0);
            s0 = fmaf(v[0][j0 + 2], kw2, s0);
            s0 = fmaf(v[1][j0],     kw3, s0);
            s0 = fmaf(v[1][j0 + 1], kw4, s0);
            s0 = fmaf(v[1][j0 + 2], kw5, s0);
            s0 = fmaf(v[2][j0],     kw6, s0);
            s0 = fmaf(v[2][j0 + 1], kw7, s0);
            s0 = fmaf(v[2][j0 + 2], kw8, s0);
            float s1 = v[0][j1] * kw0;
            s1 = fmaf(v[0][j1 + 1], kw1, s1);
            s1 = fmaf(v[0][j1 + 2], kw2, s1);
            s1 = fmaf(v[1][j1],     kw3, s1);
            s1 = fmaf(v[1][j1 + 1], kw4, s1);
            s1 = fmaf(v[1][j1 + 2], kw5, s1);
            s1 = fmaf(v[2][j1],     kw6, s1);
            s1 = fmaf(v[2][j1 + 1], kw7, s1);
            s1 = fmaf(v[2][j1 + 2], kw8, s1);
            __hip_bfloat16 h0b = __float2bfloat16(s0);
            __hip_bfloat16 h1b = __float2bfloat16(s1);
            pk[pr] = (unsigned)*reinterpret_cast<unsigned short*>(&h0b)
                   | ((unsigned)*reinterpret_cast<unsigned short*>(&h1b) << 16);
        }
        unsigned short* dst = xplane + (size_t)(t * 16 + r) * WW + cc;
        *reinterpret_cast<unsigned*>(dst)     = pk[0];
        *reinterpret_cast<unsigned*>(dst + 2) = pk[1];
        *reinterpret_cast<unsigned*>(dst + 4) = pk[2];
    };

    // ---- pipelined schedule ----
    LOADG(0, gA);
    DSWRITE(0, gA);
    LOADG(1, gB);
    __syncthreads();

    #pragma unroll
    for (int t = 0; t < 6; ++t) {
        if (t + 2 < 6) LOADG(t + 2, (t & 1) ? gB : gA);   // static after unroll
        COMPUTE(t & 1, t);
        if (t + 1 < 6) DSWRITE((t + 1) & 1, (t & 1) ? gA : gB);
        __syncthreads();
    }
}

// ---------------------------------------------------------------------------
// Kernel B (R13 — verified): pointwise MFMA, 3 h-tiles/block, software-
// pipelined staging, nontemporal stores. Grid 768, XCD-swizzled.
// ---------------------------------------------------------------------------
__global__ __launch_bounds__(256, 3)
void pw_kernel(const unsigned short* __restrict__ xn,
               const unsigned short* __restrict__ wper,
               const float* __restrict__ invp, const float* __restrict__ biasp,
               float* __restrict__ out)
{
    __shared__ __align__(16) unsigned char xnb[128 * 256];
    const int tid = threadIdx.x;

    const unsigned wg  = blockIdx.x;
    const unsigned nid = (wg & 7u) * 96u + (wg >> 3);
    const int tw  = nid % 6u;
    const int thg = (nid / 6u) % 4u;
    const int b   = nid / 24u;
    const int w0  = tw * 16;

    const int lane   = tid & 63;
    const int wv     = tid >> 6;
    const int lo     = lane & 15;
    const int hi     = lane >> 4;
    const int o_base = wv * 32;

    bf16x8_t wfrag[2][4];
    #pragma unroll
    for (int t2 = 0; t2 < 2; ++t2)
        #pragma unroll
        for (int kc = 0; kc < 4; ++kc)
            wfrag[t2][kc] = *reinterpret_cast<const bf16x8_t*>(
                wper + (size_t)(o_base + t2 * 16 + lo) * CC + kc * 32 + hi * 8);

    float iv2[2], bs2[2];
    #pragma unroll
    for (int t2 = 0; t2 < 2; ++t2) {
        iv2[t2] = invp[o_base + t2 * 16 + lo];
        bs2[t2] = biasp[o_base + t2 * 16 + lo];
    }

    const int cs4 = tid >> 3;
    const int py  = tid & 7;
    const unsigned short* src_base =
        xn + (size_t)(b * CC + cs4 * 4) * (HH * WW) + (size_t)py * WW + w0;

    unsigned dLA[4][4], dRA[4][4], dLB[4][4], dRB[4][4];

    auto LOADREGS = [&](int t, unsigned (*dL)[4], unsigned (*dR)[4]) {
        const unsigned short* s0 = src_base + (size_t)((thg * 3 + t) * 8) * WW;
        #pragma unroll
        for (int q = 0; q < 4; ++q) {
            const unsigned short* src = s0 + (size_t)q * (HH * WW);
            u32x4_t L = *(const u32x4_t*)src;
            u32x4_t R = *(const u32x4_t*)(src + 8);
            dL[q][0]=L.x; dL[q][1]=L.y; dL[q][2]=L.z; dL[q][3]=L.w;
            dR[q][0]=R.x; dR[q][1]=R.y; dR[q][2]=R.z; dR[q][3]=R.w;
        }
    };

    auto WRITE_LDS = [&](unsigned (*dL)[4], unsigned (*dR)[4]) {
        #pragma unroll
        for (int o8 = 0; o8 < 2; ++o8) {
            #pragma unroll
            for (int j = 0; j < 4; ++j) {
                const unsigned d0 = o8 ? dR[0][j] : dL[0][j];
                const unsigned d1 = o8 ? dR[1][j] : dL[1][j];
                const unsigned d2 = o8 ? dR[2][j] : dL[2][j];
                const unsigned d3 = o8 ? dR[3][j] : dL[3][j];
                u32x2_t we, wo;
                we.x = __builtin_amdgcn_perm(d1, d0, 0x05040100u);
                we.y = __builtin_amdgcn_perm(d3, d2, 0x05040100u);
                wo.x = __builtin_amdgcn_perm(d1, d0, 0x07060302u);
                wo.y = __builtin_amdgcn_perm(d3, d2, 0x07060302u);
                const int pe = py * 16 + o8 * 8 + 2 * j;
                const int po = pe + 1;
                *reinterpret_cast<u32x2_t*>(&xnb[(unsigned)pe * 256 +
                    (((unsigned)cs4 * 8) ^ (((unsigned)pe & 7u) << 4))]) = we;
                *reinterpret_cast<u32x2_t*>(&xnb[(unsigned)po * 256 +
                    (((unsigned)cs4 * 8) ^ (((unsigned)po & 7u) << 4))]) = wo;
            }
        }
    };

    auto COMPUTE = [&](int t) {
        const int h0 = (thg * 3 + t) * 8;
        f32x4_t acc[8][2];
        #pragma unroll
        for (int pt = 0; pt < 8; ++pt) {
            acc[pt][0] = (f32x4_t){0.f, 0.f, 0.f, 0.f};
            acc[pt][1] = (f32x4_t){0.f, 0.f, 0.f, 0.f};
        }
        #pragma unroll
        for (int pt = 0; pt < 8; ++pt) {
            const unsigned rowbase = (unsigned)(pt * 16 + lo) * 256;
            const unsigned sw = (unsigned)((lo & 7) << 4);
            #pragma unroll
            for (int kc = 0; kc < 4; ++kc) {
                bf16x8_t xfrag = *reinterpret_cast<const bf16x8_t*>(
                    &xnb[rowbase + (((unsigned)(kc * 64 + hi * 16)) ^ sw)]);
                acc[pt][0] = __builtin_amdgcn_mfma_f32_16x16x32_bf16(
                    xfrag, wfrag[0][kc], acc[pt][0], 0, 0, 0);
                acc[pt][1] = __builtin_amdgcn_mfma_f32_16x16x32_bf16(
                    xfrag, wfrag[1][kc], acc[pt][1], 0, 0, 0);
            }
        }
        #pragma unroll
        for (int pt = 0; pt < 8; ++pt) {
            const int hrow = h0 + pt;
            #pragma unroll
            for (int t2 = 0; t2 < 2; ++t2) {
                const int o = o_base + t2 * 16 + lo;
                f32x4_t vv;
                #pragma unroll
                for (int rix = 0; rix < 4; ++rix)
                    vv[rix] = fmaxf(fmaf(acc[pt][t2][rix], iv2[t2], bs2[t2]), 0.f);
                __builtin_nontemporal_store(vv, reinterpret_cast<f32x4_t*>(
                    out + ((size_t)(b * CC + o) * HH + hrow) * WW + w0 + hi * 4));
            }
        }
    };

    LOADREGS(0, dLA, dRA);
    WRITE_LDS(dLA, dRA);
    LOADREGS(1, dLB, dRB);
    __syncthreads();
    COMPUTE(0);
    __syncthreads();
    WRITE_LDS(dLB, dRB);
    LOADREGS(2, dLA, dRA);
    __syncthreads();
    COMPUTE(1);
    __syncthreads();
    WRITE_LDS(dLA, dRA);
    __syncthreads();
    COMPUTE(2);
}

// ---------------------------------------------------------------------------
// Fallback (ws too small): R5 fused kernel.
// ---------------------------------------------------------------------------
__global__ __launch_bounds__(256, 3)
void fused_main(const float* __restrict__ x, const float* __restrict__ kk,
                const unsigned short* __restrict__ wper,
                const float* __restrict__ invp, const float* __restrict__ biasp,
                float* __restrict__ out)
{
    __shared__ __align__(16) unsigned char xnb[128 * 256];
    const int tid = threadIdx.x;
    const unsigned wg  = blockIdx.x;
    const unsigned nid = (wg & 7u) * 288u + (wg >> 3);
    const int bx = nid % 6u;
    const int by = (nid / 6u) % 12u;
    const int bb = nid / 72u;
    const int w0 = bx * 16;
    const int h0 = by * 8;
    {
        const int wq = tid & 3;
        const int cp = tid >> 2;
        const int s  = cp << 1;
        const int kc = s >> 5, rr = s & 31, gg = rr >> 3, jj = rr & 7;
        const int cA = kc * 32 + gg * 4 + (jj & 3) + 16 * (jj >> 2);
        const int gw = w0 + wq * 4;
        const bool l_edge = (gw == 0);
        const bool r_edge = (gw + 4 >= WW);
        const float* planeA = x + (size_t)(bb * CC + cA) * (HH * WW);
        float kwA[9], kwB[9];
        {
            const float* kp = kk + (size_t)(bb * CC + cA) * 9;
            f32x4u_t q0 = *(const f32x4u_t*)(kp + 0);
            f32x4u_t q1 = *(const f32x4u_t*)(kp + 4);
            f32x4u_t q2 = *(const f32x4u_t*)(kp + 8);
            f32x4u_t q3 = *(const f32x4u_t*)(kp + 12);
            float     e16 = kp[16], e17 = kp[17];
            kwA[0]=q0.x; kwA[1]=q0.y; kwA[2]=q0.z; kwA[3]=q0.w;
            kwA[4]=q1.x; kwA[5]=q1.y; kwA[6]=q1.z; kwA[7]=q1.w;
            kwA[8]=q2.x;
            kwB[0]=q2.y; kwB[1]=q2.z; kwB[2]=q2.w;
            kwB[3]=q3.x; kwB[4]=q3.y; kwB[5]=q3.z; kwB[6]=q3.w;
            kwB[7]=e16;  kwB[8]=e17;
        }
        float xd[2][10][6];
        #pragma unroll
        for (int q = 0; q < 2; ++q) {
            const float* plane = planeA + q * (HH * WW);
            #pragma unroll
            for (int r = 0; r < 10; ++r) {
                const int row = h0 - 1 + r;
                const bool valid = (row >= 0) && (row < HH);
                const int rrow = row < 0 ? 0 : (row >= HH ? HH - 1 : row);
                const float* rp = plane + rrow * WW + gw;
                f32x4_t M = *(const f32x4_t*)rp;
                float vl = rp[l_edge ? 0 : -1];
                float vr = rp[r_edge ? 3 : 4];
                xd[q][r][0] = (valid && !l_edge) ? vl : 0.f;
                xd[q][r][1] = valid ? M.x : 0.f;
                xd[q][r][2] = valid ? M.y : 0.f;
                xd[q][r][3] = valid ? M.z : 0.f;
                xd[q][r][4] = valid ? M.w : 0.f;
                xd[q][r][5] = (valid && !r_edge) ? vr : 0.f;
            }
        }
        #pragma unroll
        for (int py = 0; py < 8; ++py) {
            #pragma unroll
            for (int i = 0; i < 4; ++i) {
                float sA = 0.f, sB = 0.f;
                #pragma unroll
                for (int t = 0; t < 3; ++t) {
                    sA = fmaf(xd[0][py + 0][i + t], kwA[t],     sA);
                    sA = fmaf(xd[0][py + 1][i + t], kwA[3 + t], sA);
                    sA = fmaf(xd[0][py + 2][i + t], kwA[6 + t], sA);
                    sB = fmaf(xd[1][py + 0][i + t], kwB[t],     sB);
                    sB = fmaf(xd[1][py + 1][i + t], kwB[3 + t], sB);
                    sB = fmaf(xd[1][py + 2][i + t], kwB[6 + t], sB);
                }
                __hip_bfloat16 hA = __float2bfloat16(sA);
                __hip_bfloat16 hB = __float2bfloat16(sB);
                unsigned pk = (unsigned)*reinterpret_cast<unsigned short*>(&hA)
                            | ((unsigned)*reinterpret_cast<unsigned short*>(&hB) << 16);
                const int p = py * 16 + wq * 4 + i;
                const unsigned boff = ((unsigned)(cp << 2)) ^ (((unsigned)p & 7u) << 4);
                *reinterpret_cast<unsigned*>(&xnb[(unsigned)p * 256 + boff]) = pk;
            }
        }
    }
    __syncthreads();
    {
        const int lane   = tid & 63;
        const int wv     = tid >> 6;
        const int lo     = lane & 15;
        const int hi     = lane >> 4;
        const int o_base = wv * 32;
        bf16x8_t afrag[2][4];
        #pragma unroll
        for (int t2 = 0; t2 < 2; ++t2)
            #pragma unroll
            for (int kc = 0; kc < 4; ++kc)
                afrag[t2][kc] = *reinterpret_cast<const bf16x8_t*>(
                    wper + (size_t)(o_base + t2 * 16 + lo) * CC + kc * 32 + hi * 8);
        f32x4_t acc[8][2];
        #pragma unroll
        for (int pt = 0; pt < 8; ++pt) {
            acc[pt][0] = (f32x4_t){0.f, 0.f, 0.f, 0.f};
            acc[pt][1] = (f32x4_t){0.f, 0.f, 0.f, 0.f};
        }
        #pragma unroll
        for (int pt = 0; pt < 8; ++pt) {
            const unsigned rowbase = (unsigned)(pt * 16 + lo) * 256;
            const unsigned sw = (unsigned)((lo & 7) << 4);
            #pragma unroll
            for (int kc = 0; kc < 4; ++kc) {
                bf16x8_t bfrag = *reinterpret_cast<const bf16x8_t*>(
                    &xnb[rowbase + (((unsigned)(kc * 64 + hi * 16)) ^ sw)]);
                acc[pt][0] = __builtin_amdgcn_mfma_f32_16x16x32_bf16(
                    afrag[0][kc], bfrag, acc[pt][0], 0, 0, 0);
                acc[pt][1] = __builtin_amdgcn_mfma_f32_16x16x32_bf16(
                    afrag[1][kc], bfrag, acc[pt][1], 0, 0, 0);
            }
        }
        float iv[2][4], bs[2][4];
        #pragma unroll
        for (int t2 = 0; t2 < 2; ++t2)
            #pragma unroll
            for (int r = 0; r < 4; ++r) {
                const int o = o_base + t2 * 16 + hi * 4 + r;
                iv[t2][r] = invp[o];
                bs[t2][r] = biasp[o];
            }
        #pragma unroll
        for (int pt = 0; pt < 8; ++pt) {
            const int hrow = h0 + pt;
            #pragma unroll
            for (int t2 = 0; t2 < 2; ++t2) {
                #pragma unroll
                for (int r = 0; r < 4; ++r) {
                    const int o = o_base + t2 * 16 + hi * 4 + r;
                    float val = fmaf(acc[pt][t2][r], iv[t2][r], bs[t2][r]);
                    val = fmaxf(val, 0.f);
                    out[((size_t)(bb * CC + o) * HH + hrow) * WW + w0 + lo] = val;
                }
            }
        }
    }
}

extern "C" void kernel_launch(void* const* d_in, const int* in_sizes, int n_in,
                              void* d_out, int out_size, void* d_ws, size_t ws_size,
                              hipStream_t stream) {
    const float* x   = (const float*)d_in[0];
    const float* kk  = (const float*)d_in[1];
    const float* pwt = (const float*)d_in[2];
    const float* g   = (const float*)d_in[3];
    const float* b   = (const float*)d_in[4];
    const float* m   = (const float*)d_in[5];
    const float* v   = (const float*)d_in[6];
    float* out = (float*)d_out;

    unsigned short* wper = (unsigned short*)d_ws;                 // 32 KB
    float* inv  = (float*)((char*)d_ws + 32768);                  // 512 B
    float* bias = (float*)((char*)d_ws + 32768 + 512);            // 512 B
    unsigned short* xn = (unsigned short*)((char*)d_ws + 36864);  // 75.5 MB
    const size_t need = 36864 + (size_t)BB * CC * HH * WW * 2;

    prep_kernel<<<64, 256, 0, stream>>>(pwt, g, b, m, v, wper, inv, bias);
    if (ws_size >= need) {
        dw_kernel<<<dim3(4096), 256, 0, stream>>>(x, kk, xn);
        pw_kernel<<<dim3(768), 256, 0, stream>>>(xn, wper, inv, bias, out);
    } else {
        fused_main<<<dim3(2304), 256, 0, stream>>>(x, kk, wper, inv, bias, out);
    }
}

// Round 17
// 94.551 us; speedup vs baseline: 1.0081x; 1.0081x over previous
//
#include <hip/hip_runtime.h>
#include <hip/hip_bf16.h>

#define BB 32
#define CC 128
#define HH 96
#define WW 96
#define BN_EPS 1e-5f

typedef __attribute__((ext_vector_type(8))) short bf16x8_t;
typedef __attribute__((ext_vector_type(4))) float f32x4_t;
typedef __attribute__((ext_vector_type(4), aligned(4))) float f32x4u_t;
typedef __attribute__((ext_vector_type(2))) unsigned int u32x2_t;
typedef __attribute__((ext_vector_type(4))) unsigned int u32x4_t;

typedef const float __attribute__((address_space(1))) gfloat_t;
typedef float __attribute__((address_space(3))) sfloat_t;

// ---------------------------------------------------------------------------
// Prep: W fp32 -> bf16, k-permuted (verified). BN folded to inv/bias.
// ---------------------------------------------------------------------------
__global__ __launch_bounds__(256)
void prep_kernel(const float* __restrict__ pw,
                 const float* __restrict__ g, const float* __restrict__ b,
                 const float* __restrict__ m, const float* __restrict__ v,
                 unsigned short* __restrict__ wper,
                 float* __restrict__ inv, float* __restrict__ bias)
{
    int t = blockIdx.x * 256 + threadIdx.x;
    if (t < CC * CC) {
        int o = t >> 7, cidx = t & 127;
        int kc = cidx >> 5, r = cidx & 31, gg = r >> 3, j = r & 7;
        int c = kc * 32 + gg * 4 + (j & 3) + 16 * (j >> 2);
        __hip_bfloat16 h = __float2bfloat16(pw[o * CC + c]);
        wper[o * CC + cidx] = *reinterpret_cast<unsigned short*>(&h);
    }
    if (t < CC) {
        float iv = g[t] * rsqrtf(v[t] + BN_EPS);
        inv[t] = iv;
        bias[t] = b[t] - m[t] * iv;
    }
}

// ---------------------------------------------------------------------------
// Kernel A (R17): depthwise 3x3, block = (b,cs) full plane, 6 slab iters.
// Staging via global_load_lds DMA (width 16) into LINEAR double-buffered LDS
// — no VGPR writeback, so the scheduler cannot sink the loads (the R4-R16
// pathology). DMA issues for slab t+2 right after the barrier that ends
// iter t; the barrier's vmcnt(0) drain at the END of iter t+1 lands it,
// giving one full COMPUTE of flight time (m97 pattern).
// Boundary rows: DMA source clamped to [0,95]; compute zeroes the halo row
// at compile-time-folded (t,r) conditions. LDS stride 96 (linear, DMA req).
// Grid 4096 = 32b x 128cs, chunked XCD swizzle.
// ---------------------------------------------------------------------------
__global__ __launch_bounds__(256, 6)
void dw_kernel(const float* __restrict__ x, const float* __restrict__ kk,
               unsigned short* __restrict__ xn)
{
    __shared__ __align__(16) float tile[2][18 * 96];     // 2 x 6912 B, linear
    const int tid = threadIdx.x;

    const unsigned wg  = blockIdx.x;
    const unsigned bid = (wg & 7u) * 512u + (wg >> 3);   // bijective on [0,4096)
    const int cs = bid & 127;
    const int b  = bid >> 7;

    // storage -> actual channel permutation (blockIdx-derived -> SGPR)
    const int kc = cs >> 5, rr2 = cs & 31, gg = rr2 >> 3, jj = rr2 & 7;
    const int c = kc * 32 + gg * 4 + (jj & 3) + 16 * (jj >> 2);

    const float* plane = x + (size_t)(b * CC + c) * (HH * WW);
    unsigned short* xplane = xn + (size_t)(b * CC + cs) * (HH * WW);

    // block-uniform weights -> scalar loads
    const float* kp = kk + (size_t)(b * CC + c) * 9;
    const float kw0 = kp[0], kw1 = kp[1], kw2 = kp[2];
    const float kw3 = kp[3], kw4 = kp[4], kw5 = kp[5];
    const float kw6 = kp[6], kw7 = kp[7], kw8 = kp[8];

    // staging slots: 432 x 16B (18 rows x 24 quads); slot s -> (s/24, (s%24)*4)
    const int rowA = tid / 24;
    const int colA = (tid % 24) * 4;
    const int sB   = tid + 256;                 // valid iff tid < 176
    const int rowB = sB / 24;
    const int colB = (sB % 24) * 4;
    const bool hasB = (sB < 432);

    auto STAGE = [&](int t, int buf) {
        int hA = t * 16 - 1 + rowA;
        hA = hA < 0 ? 0 : (hA > HH - 1 ? HH - 1 : hA);   // clamp; compute zeroes halo
        __builtin_amdgcn_global_load_lds(
            (gfloat_t*)(plane + (size_t)hA * WW + colA),
            (sfloat_t*)&tile[buf][tid * 4], 16, 0, 0);
        if (hasB) {
            int hB = t * 16 - 1 + rowB;
            hB = hB < 0 ? 0 : (hB > HH - 1 ? HH - 1 : hB);
            __builtin_amdgcn_global_load_lds(
                (gfloat_t*)(plane + (size_t)hB * WW + colB),
                (sfloat_t*)&tile[buf][sB * 4], 16, 0, 0);
        }
    };

    const int r  = tid >> 4;            // output row in slab, 0..15
    const int cc = (tid & 15) * 6;      // first col, 0..90

    auto COMPUTE = [&](int buf, int t) {
        float v[3][8];
        #pragma unroll
        for (int dr = 0; dr < 3; ++dr) {
            const float* trow = &tile[buf][(r + dr) * 96];
            const float lv = trow[cc == 0 ? 0 : cc - 1];
            v[dr][0] = (cc == 0) ? 0.f : lv;
            #pragma unroll
            for (int i = 0; i < 6; ++i) v[dr][1 + i] = trow[cc + i];
            const float rv = trow[cc == 90 ? 95 : cc + 6];
            v[dr][7] = (cc == 90) ? 0.f : rv;
        }
        // halo rows (DMA source was clamped): zero them. t is a literal after
        // unroll -> conditions fold to the two boundary slabs only.
        if (t == 0 && r == 0) {
            #pragma unroll
            for (int i = 0; i < 8; ++i) v[0][i] = 0.f;
        }
        if (t == 5 && r == 15) {
            #pragma unroll
            for (int i = 0; i < 8; ++i) v[2][i] = 0.f;
        }
        unsigned pk[3];
        #pragma unroll
        for (int pr = 0; pr < 3; ++pr) {
            const int j0 = 2 * pr, j1 = j0 + 1;
            float s0 = v[0][j0] * kw0;
            s0 = fmaf(v[0][j0 + 1], kw1, s0);
            s0 = fmaf(v[0][j0 + 2], kw2, s0);
            s0 = fmaf(v[1][j0],     kw3, s0);
            s0 = fmaf(v[1][j0 + 1], kw4, s0);
            s0 = fmaf(v[1][j0 + 2], kw5, s0);
            s0 = fmaf(v[2][j0],     kw6, s0);
            s0 = fmaf(v[2][j0 + 1], kw7, s0);
            s0 = fmaf(v[2][j0 + 2], kw8, s0);
            float s1 = v[0][j1] * kw0;
            s1 = fmaf(v[0][j1 + 1], kw1, s1);
            s1 = fmaf(v[0][j1 + 2], kw2, s1);
            s1 = fmaf(v[1][j1],     kw3, s1);
            s1 = fmaf(v[1][j1 + 1], kw4, s1);
            s1 = fmaf(v[1][j1 + 2], kw5, s1);
            s1 = fmaf(v[2][j1],     kw6, s1);
            s1 = fmaf(v[2][j1 + 1], kw7, s1);
            s1 = fmaf(v[2][j1 + 2], kw8, s1);
            __hip_bfloat16 h0b = __float2bfloat16(s0);
            __hip_bfloat16 h1b = __float2bfloat16(s1);
            pk[pr] = (unsigned)*reinterpret_cast<unsigned short*>(&h0b)
                   | ((unsigned)*reinterpret_cast<unsigned short*>(&h1b) << 16);
        }
        unsigned short* dst = xplane + (size_t)(t * 16 + r) * WW + cc;
        *reinterpret_cast<unsigned*>(dst)     = pk[0];
        *reinterpret_cast<unsigned*>(dst + 2) = pk[1];
        *reinterpret_cast<unsigned*>(dst + 4) = pk[2];
    };

    // ---- pipelined schedule: DMA(t+1) in flight during COMPUTE(t) ----
    STAGE(0, 0);
    __syncthreads();            // drains DMA(0)
    STAGE(1, 1);                // flies under COMPUTE(0)

    #pragma unroll
    for (int t = 0; t < 6; ++t) {
        COMPUTE(t & 1, t);
        __syncthreads();        // drains DMA(t+1); LDS-read fence for reuse
        if (t + 2 < 6) STAGE(t + 2, t & 1);
    }
}

// ---------------------------------------------------------------------------
// Kernel B (R13 — verified): pointwise MFMA, 3 h-tiles/block, software-
// pipelined staging, nontemporal stores. Grid 768, XCD-swizzled.
// ---------------------------------------------------------------------------
__global__ __launch_bounds__(256, 3)
void pw_kernel(const unsigned short* __restrict__ xn,
               const unsigned short* __restrict__ wper,
               const float* __restrict__ invp, const float* __restrict__ biasp,
               float* __restrict__ out)
{
    __shared__ __align__(16) unsigned char xnb[128 * 256];
    const int tid = threadIdx.x;

    const unsigned wg  = blockIdx.x;
    const unsigned nid = (wg & 7u) * 96u + (wg >> 3);
    const int tw  = nid % 6u;
    const int thg = (nid / 6u) % 4u;
    const int b   = nid / 24u;
    const int w0  = tw * 16;

    const int lane   = tid & 63;
    const int wv     = tid >> 6;
    const int lo     = lane & 15;
    const int hi     = lane >> 4;
    const int o_base = wv * 32;

    bf16x8_t wfrag[2][4];
    #pragma unroll
    for (int t2 = 0; t2 < 2; ++t2)
        #pragma unroll
        for (int kc = 0; kc < 4; ++kc)
            wfrag[t2][kc] = *reinterpret_cast<const bf16x8_t*>(
                wper + (size_t)(o_base + t2 * 16 + lo) * CC + kc * 32 + hi * 8);

    float iv2[2], bs2[2];
    #pragma unroll
    for (int t2 = 0; t2 < 2; ++t2) {
        iv2[t2] = invp[o_base + t2 * 16 + lo];
        bs2[t2] = biasp[o_base + t2 * 16 + lo];
    }

    const int cs4 = tid >> 3;
    const int py  = tid & 7;
    const unsigned short* src_base =
        xn + (size_t)(b * CC + cs4 * 4) * (HH * WW) + (size_t)py * WW + w0;

    unsigned dLA[4][4], dRA[4][4], dLB[4][4], dRB[4][4];

    auto LOADREGS = [&](int t, unsigned (*dL)[4], unsigned (*dR)[4]) {
        const unsigned short* s0 = src_base + (size_t)((thg * 3 + t) * 8) * WW;
        #pragma unroll
        for (int q = 0; q < 4; ++q) {
            const unsigned short* src = s0 + (size_t)q * (HH * WW);
            u32x4_t L = *(const u32x4_t*)src;
            u32x4_t R = *(const u32x4_t*)(src + 8);
            dL[q][0]=L.x; dL[q][1]=L.y; dL[q][2]=L.z; dL[q][3]=L.w;
            dR[q][0]=R.x; dR[q][1]=R.y; dR[q][2]=R.z; dR[q][3]=R.w;
        }
    };

    auto WRITE_LDS = [&](unsigned (*dL)[4], unsigned (*dR)[4]) {
        #pragma unroll
        for (int o8 = 0; o8 < 2; ++o8) {
            #pragma unroll
            for (int j = 0; j < 4; ++j) {
                const unsigned d0 = o8 ? dR[0][j] : dL[0][j];
                const unsigned d1 = o8 ? dR[1][j] : dL[1][j];
                const unsigned d2 = o8 ? dR[2][j] : dL[2][j];
                const unsigned d3 = o8 ? dR[3][j] : dL[3][j];
                u32x2_t we, wo;
                we.x = __builtin_amdgcn_perm(d1, d0, 0x05040100u);
                we.y = __builtin_amdgcn_perm(d3, d2, 0x05040100u);
                wo.x = __builtin_amdgcn_perm(d1, d0, 0x07060302u);
                wo.y = __builtin_amdgcn_perm(d3, d2, 0x07060302u);
                const int pe = py * 16 + o8 * 8 + 2 * j;
                const int po = pe + 1;
                *reinterpret_cast<u32x2_t*>(&xnb[(unsigned)pe * 256 +
                    (((unsigned)cs4 * 8) ^ (((unsigned)pe & 7u) << 4))]) = we;
                *reinterpret_cast<u32x2_t*>(&xnb[(unsigned)po * 256 +
                    (((unsigned)cs4 * 8) ^ (((unsigned)po & 7u) << 4))]) = wo;
            }
        }
    };

    auto COMPUTE = [&](int t) {
        const int h0 = (thg * 3 + t) * 8;
        f32x4_t acc[8][2];
        #pragma unroll
        for (int pt = 0; pt < 8; ++pt) {
            acc[pt][0] = (f32x4_t){0.f, 0.f, 0.f, 0.f};
            acc[pt][1] = (f32x4_t){0.f, 0.f, 0.f, 0.f};
        }
        #pragma unroll
        for (int pt = 0; pt < 8; ++pt) {
            const unsigned rowbase = (unsigned)(pt * 16 + lo) * 256;
            const unsigned sw = (unsigned)((lo & 7) << 4);
            #pragma unroll
            for (int kc = 0; kc < 4; ++kc) {
                bf16x8_t xfrag = *reinterpret_cast<const bf16x8_t*>(
                    &xnb[rowbase + (((unsigned)(kc * 64 + hi * 16)) ^ sw)]);
                acc[pt][0] = __builtin_amdgcn_mfma_f32_16x16x32_bf16(
                    xfrag, wfrag[0][kc], acc[pt][0], 0, 0, 0);
                acc[pt][1] = __builtin_amdgcn_mfma_f32_16x16x32_bf16(
                    xfrag, wfrag[1][kc], acc[pt][1], 0, 0, 0);
            }
        }
        #pragma unroll
        for (int pt = 0; pt < 8; ++pt) {
            const int hrow = h0 + pt;
            #pragma unroll
            for (int t2 = 0; t2 < 2; ++t2) {
                const int o = o_base + t2 * 16 + lo;
                f32x4_t vv;
                #pragma unroll
                for (int rix = 0; rix < 4; ++rix)
                    vv[rix] = fmaxf(fmaf(acc[pt][t2][rix], iv2[t2], bs2[t2]), 0.f);
                __builtin_nontemporal_store(vv, reinterpret_cast<f32x4_t*>(
                    out + ((size_t)(b * CC + o) * HH + hrow) * WW + w0 + hi * 4));
            }
        }
    };

    LOADREGS(0, dLA, dRA);
    WRITE_LDS(dLA, dRA);
    LOADREGS(1, dLB, dRB);
    __syncthreads();
    COMPUTE(0);
    __syncthreads();
    WRITE_LDS(dLB, dRB);
    LOADREGS(2, dLA, dRA);
    __syncthreads();
    COMPUTE(1);
    __syncthreads();
    WRITE_LDS(dLA, dRA);
    __syncthreads();
    COMPUTE(2);
}

// ---------------------------------------------------------------------------
// Fallback (ws too small): R5 fused kernel.
// ---------------------------------------------------------------------------
__global__ __launch_bounds__(256, 3)
void fused_main(const float* __restrict__ x, const float* __restrict__ kk,
                const unsigned short* __restrict__ wper,
                const float* __restrict__ invp, const float* __restrict__ biasp,
                float* __restrict__ out)
{
    __shared__ __align__(16) unsigned char xnb[128 * 256];
    const int tid = threadIdx.x;
    const unsigned wg  = blockIdx.x;
    const unsigned nid = (wg & 7u) * 288u + (wg >> 3);
    const int bx = nid % 6u;
    const int by = (nid / 6u) % 12u;
    const int bb = nid / 72u;
    const int w0 = bx * 16;
    const int h0 = by * 8;
    {
        const int wq = tid & 3;
        const int cp = tid >> 2;
        const int s  = cp << 1;
        const int kc = s >> 5, rr = s & 31, gg = rr >> 3, jj = rr & 7;
        const int cA = kc * 32 + gg * 4 + (jj & 3) + 16 * (jj >> 2);
        const int gw = w0 + wq * 4;
        const bool l_edge = (gw == 0);
        const bool r_edge = (gw + 4 >= WW);
        const float* planeA = x + (size_t)(bb * CC + cA) * (HH * WW);
        float kwA[9], kwB[9];
        {
            const float* kp = kk + (size_t)(bb * CC + cA) * 9;
            f32x4u_t q0 = *(const f32x4u_t*)(kp + 0);
            f32x4u_t q1 = *(const f32x4u_t*)(kp + 4);
            f32x4u_t q2 = *(const f32x4u_t*)(kp + 8);
            f32x4u_t q3 = *(const f32x4u_t*)(kp + 12);
            float     e16 = kp[16], e17 = kp[17];
            kwA[0]=q0.x; kwA[1]=q0.y; kwA[2]=q0.z; kwA[3]=q0.w;
            kwA[4]=q1.x; kwA[5]=q1.y; kwA[6]=q1.z; kwA[7]=q1.w;
            kwA[8]=q2.x;
            kwB[0]=q2.y; kwB[1]=q2.z; kwB[2]=q2.w;
            kwB[3]=q3.x; kwB[4]=q3.y; kwB[5]=q3.z; kwB[6]=q3.w;
            kwB[7]=e16;  kwB[8]=e17;
        }
        float xd[2][10][6];
        #pragma unroll
        for (int q = 0; q < 2; ++q) {
            const float* plane = planeA + q * (HH * WW);
            #pragma unroll
            for (int r = 0; r < 10; ++r) {
                const int row = h0 - 1 + r;
                const bool valid = (row >= 0) && (row < HH);
                const int rrow = row < 0 ? 0 : (row >= HH ? HH - 1 : row);
                const float* rp = plane + rrow * WW + gw;
                f32x4_t M = *(const f32x4_t*)rp;
                float vl = rp[l_edge ? 0 : -1];
                float vr = rp[r_edge ? 3 : 4];
                xd[q][r][0] = (valid && !l_edge) ? vl : 0.f;
                xd[q][r][1] = valid ? M.x : 0.f;
                xd[q][r][2] = valid ? M.y : 0.f;
                xd[q][r][3] = valid ? M.z : 0.f;
                xd[q][r][4] = valid ? M.w : 0.f;
                xd[q][r][5] = (valid && !r_edge) ? vr : 0.f;
            }
        }
        #pragma unroll
        for (int py = 0; py < 8; ++py) {
            #pragma unroll
            for (int i = 0; i < 4; ++i) {
                float sA = 0.f, sB = 0.f;
                #pragma unroll
                for (int t = 0; t < 3; ++t) {
                    sA = fmaf(xd[0][py + 0][i + t], kwA[t],     sA);
                    sA = fmaf(xd[0][py + 1][i + t], kwA[3 + t], sA);
                    sA = fmaf(xd[0][py + 2][i + t], kwA[6 + t], sA);
                    sB = fmaf(xd[1][py + 0][i + t], kwB[t],     sB);
                    sB = fmaf(xd[1][py + 1][i + t], kwB[3 + t], sB);
                    sB = fmaf(xd[1][py + 2][i + t], kwB[6 + t], sB);
                }
                __hip_bfloat16 hA = __float2bfloat16(sA);
                __hip_bfloat16 hB = __float2bfloat16(sB);
                unsigned pk = (unsigned)*reinterpret_cast<unsigned short*>(&hA)
                            | ((unsigned)*reinterpret_cast<unsigned short*>(&hB) << 16);
                const int p = py * 16 + wq * 4 + i;
                const unsigned boff = ((unsigned)(cp << 2)) ^ (((unsigned)p & 7u) << 4);
                *reinterpret_cast<unsigned*>(&xnb[(unsigned)p * 256 + boff]) = pk;
            }
        }
    }
    __syncthreads();
    {
        const int lane   = tid & 63;
        const int wv     = tid >> 6;
        const int lo     = lane & 15;
        const int hi     = lane >> 4;
        const int o_base = wv * 32;
        bf16x8_t afrag[2][4];
        #pragma unroll
        for (int t2 = 0; t2 < 2; ++t2)
            #pragma unroll
            for (int kc = 0; kc < 4; ++kc)
                afrag[t2][kc] = *reinterpret_cast<const bf16x8_t*>(
                    wper + (size_t)(o_base + t2 * 16 + lo) * CC + kc * 32 + hi * 8);
        f32x4_t acc[8][2];
        #pragma unroll
        for (int pt = 0; pt < 8; ++pt) {
            acc[pt][0] = (f32x4_t){0.f, 0.f, 0.f, 0.f};
            acc[pt][1] = (f32x4_t){0.f, 0.f, 0.f, 0.f};
        }
        #pragma unroll
        for (int pt = 0; pt < 8; ++pt) {
            const unsigned rowbase = (unsigned)(pt * 16 + lo) * 256;
            const unsigned sw = (unsigned)((lo & 7) << 4);
            #pragma unroll
            for (int kc = 0; kc < 4; ++kc) {
                bf16x8_t bfrag = *reinterpret_cast<const bf16x8_t*>(
                    &xnb[rowbase + (((unsigned)(kc * 64 + hi * 16)) ^ sw)]);
                acc[pt][0] = __builtin_amdgcn_mfma_f32_16x16x32_bf16(
                    afrag[0][kc], bfrag, acc[pt][0], 0, 0, 0);
                acc[pt][1] = __builtin_amdgcn_mfma_f32_16x16x32_bf16(
                    afrag[1][kc], bfrag, acc[pt][1], 0, 0, 0);
            }
        }
        float iv[2][4], bs[2][4];
        #pragma unroll
        for (int t2 = 0; t2 < 2; ++t2)
            #pragma unroll
            for (int r = 0; r < 4; ++r) {
                const int o = o_base + t2 * 16 + hi * 4 + r;
                iv[t2][r] = invp[o];
                bs[t2][r] = biasp[o];
            }
        #pragma unroll
        for (int pt = 0; pt < 8; ++pt) {
            const int hrow = h0 + pt;
            #pragma unroll
            for (int t2 = 0; t2 < 2; ++t2) {
                #pragma unroll
                for (int r = 0; r < 4; ++r) {
                    const int o = o_base + t2 * 16 + hi * 4 + r;
                    float val = fmaf(acc[pt][t2][r], iv[t2][r], bs[t2][r]);
                    val = fmaxf(val, 0.f);
                    out[((size_t)(bb * CC + o) * HH + hrow) * WW + w0 + lo] = val;
                }
            }
        }
    }
}

extern "C" void kernel_launch(void* const* d_in, const int* in_sizes, int n_in,
                              void* d_out, int out_size, void* d_ws, size_t ws_size,
                              hipStream_t stream) {
    const float* x   = (const float*)d_in[0];
    const float* kk  = (const float*)d_in[1];
    const float* pwt = (const float*)d_in[2];
    const float* g   = (const float*)d_in[3];
    const float* b   = (const float*)d_in[4];
    const float* m   = (const float*)d_in[5];
    const float* v   = (const float*)d_in[6];
    float* out = (float*)d_out;

    unsigned short* wper = (unsigned short*)d_ws;                 // 32 KB
    float* inv  = (float*)((char*)d_ws + 32768);                  // 512 B
    float* bias = (float*)((char*)d_ws + 32768 + 512);            // 512 B
    unsigned short* xn = (unsigned short*)((char*)d_ws + 36864);  // 75.5 MB
    const size_t need = 36864 + (size_t)BB * CC * HH * WW * 2;

    prep_kernel<<<64, 256, 0, stream>>>(pwt, g, b, m, v, wper, inv, bias);
    if (ws_size >= need) {
        dw_kernel<<<dim3(4096), 256, 0, stream>>>(x, kk, xn);
        pw_kernel<<<dim3(768), 256, 0, stream>>>(xn, wper, inv, bias, out);
    } else {
        fused_main<<<dim3(2304), 256, 0, stream>>>(x, kk, wper, inv, bias, out);
    }
}